// Round 7
// baseline (237.472 us; speedup 1.0000x reference)
//
#include <hip/hip_runtime.h>
#include <hip/hip_bf16.h>

typedef __attribute__((ext_vector_type(8))) short bf16x8;
typedef __attribute__((ext_vector_type(4))) float f32x4;

constexpr int B   = 2;
constexpr int CIN = 256;
constexpr int CO  = 128;
constexpr int H = 48, W = 48;
constexpr int H2 = 96, W2 = 96;
constexpr int NPIX1 = H * W;    // 2304
constexpr int NPIX2 = H2 * W2;  // 9216
constexpr int NS = 4;           // conv split-K factor

__device__ inline ushort f2bf(float v)
{
  __hip_bfloat16 h = __float2bfloat16(v);
  return *reinterpret_cast<ushort*>(&h);
}

// ---------------- input NCHW f32 -> NHWC bf16, LDS-tiled transpose ----------------
// grid: B * (NPIX1/64) * (CIN/32)
__global__ __launch_bounds__(256) void cvt_in_t_kernel(
    const float* __restrict__ in, ushort* __restrict__ outh)
{
  int blk = blockIdx.x;
  int cg = blk & 7;
  int pc = (blk >> 3) % 36;
  int b  = blk / (8 * 36);
  int c0 = cg * 32, pix0 = pc * 64;
  int tid = threadIdx.x;
  __shared__ float lt[32][65];
#pragma unroll
  for (int r = 0; r < 8; r++) {
    int c_l = r * 4 + (tid >> 6), px = tid & 63;
    lt[c_l][px] = in[((size_t)b * CIN + c0 + c_l) * NPIX1 + pix0 + px];
  }
  __syncthreads();
  int c_l = tid & 31;
#pragma unroll
  for (int r = 0; r < 8; r++) {
    int px = r * 8 + (tid >> 5);
    outh[((size_t)b * NPIX1 + pix0 + px) * CIN + c0 + c_l] = f2bf(lt[c_l][px]);
  }
}

// ---------------- conv weight f32 [o][ci][3][3] -> bf16 [tap][o][ci] ----------------
template<int CIg, int SH>
__global__ __launch_bounds__(256) void wtconv_kernel(
    const float* __restrict__ w, ushort* __restrict__ wt)
{
  int idx = blockIdx.x * 256 + threadIdx.x;   // 9*128*CIg
  int ci = idx & (CIg - 1);
  int o  = (idx >> SH) & 127;
  int tap = idx >> (SH + 7);
  wt[idx] = f2bf(w[((size_t)o * CIg + ci) * 9 + tap]);
}

// ---------------- conv3x3 via MFMA (implicit GEMM, split-K over ci) ----------------
template<int CIg>
__global__ __launch_bounds__(256, 4) void conv3_mfma_kernel(
    const ushort* __restrict__ xh,   // NHWC bf16 [b][48][48][CIg]
    const ushort* __restrict__ wt,   // bf16 [9][128][CIg]
    float* __restrict__ pout)        // [NS][b][128][2304]
{
  constexpr int CS = CIg / NS;
  constexpr int G  = CS / 8;
  constexpr int KC = CS / 32;
  int blk = blockIdx.x;
  int tile = blk % 36;
  int s = (blk / 36) & 3;
  int b = blk / 144;
  int th = tile / 3, tw = tile % 3;
  int h0 = th * 4, w0 = tw * 16;
  int tid = threadIdx.x, lane = tid & 63, wv = tid >> 6;
  int l15 = lane & 15, l4 = (lane >> 4) & 3;

  __shared__ ushort xt[108 * CS];
  for (int q = tid; q < 108 * G; q += 256) {
    int pixi = q / G, g = q & (G - 1);
    int rh = pixi / 18, rw = pixi - rh * 18;
    int hg = h0 - 1 + rh, wg = w0 - 1 + rw;
    uint4 v{0u, 0u, 0u, 0u};
    if (hg >= 0 && hg < H && wg >= 0 && wg < W)
      v = *(const uint4*)(xh + (size_t)(b * NPIX1 + hg * W + wg) * CIg + s * CS + g * 8);
    *(uint4*)(xt + pixi * CS + ((g ^ (pixi & (G - 1))) * 8)) = v;
  }
  __syncthreads();

  int wo = wv * 32;
  const ushort* wbase = wt + (size_t)(wo + l15) * CIg + s * CS + l4 * 8;

  f32x4 acc0[4], acc1[4];
#pragma unroll
  for (int nf = 0; nf < 4; nf++) {
    acc0[nf] = {0.f, 0.f, 0.f, 0.f};
    acc1[nf] = {0.f, 0.f, 0.f, 0.f};
  }

  bf16x8 aC0[KC], aC1[KC], aN0[KC], aN1[KC];
#pragma unroll
  for (int kc = 0; kc < KC; kc++) {
    aC0[kc] = *(const bf16x8*)(wbase + kc * 32);
    aC1[kc] = *(const bf16x8*)(wbase + 16 * CIg + kc * 32);
  }

#pragma unroll 1
  for (int tap = 0; tap < 9; ++tap) {
    if (tap < 8) {
      const ushort* wn = wbase + (size_t)(tap + 1) * 128 * CIg;
#pragma unroll
      for (int kc = 0; kc < KC; kc++) {
        aN0[kc] = *(const bf16x8*)(wn + kc * 32);
        aN1[kc] = *(const bf16x8*)(wn + 16 * CIg + kc * 32);
      }
    }
    int kh = (tap >= 6) ? 2 : ((tap >= 3) ? 1 : 0);
    int kw = tap - kh * 3;
#pragma unroll
    for (int kc = 0; kc < KC; kc++) {
#pragma unroll
      for (int nf = 0; nf < 4; nf++) {
        int pix = (nf + kh) * 18 + kw + l15;
        bf16x8 bb = *(const bf16x8*)(xt + pix * CS + (((kc * 4 + l4) ^ (pix & (G - 1))) * 8));
        acc0[nf] = __builtin_amdgcn_mfma_f32_16x16x32_bf16(aC0[kc], bb, acc0[nf], 0, 0, 0);
        acc1[nf] = __builtin_amdgcn_mfma_f32_16x16x32_bf16(aC1[kc], bb, acc1[nf], 0, 0, 0);
      }
    }
#pragma unroll
    for (int kc = 0; kc < KC; kc++) { aC0[kc] = aN0[kc]; aC1[kc] = aN1[kc]; }
  }

#pragma unroll
  for (int nf = 0; nf < 4; nf++) {
    int pixg = (h0 + nf) * W + w0 + l15;
#pragma unroll
    for (int r = 0; r < 4; r++) {
      int o = wo + l4 * 4 + r;
      pout[((size_t)(s * B + b) * CO + o) * NPIX1 + pixg] = acc0[nf][r];
      pout[((size_t)(s * B + b) * CO + o + 16) * NPIX1 + pixg] = acc1[nf][r];
    }
  }
}

// ---------------- instance-norm stats from partials -> scale/shift ----------------
__global__ __launch_bounds__(256) void in_stats_kernel(
    const float* __restrict__ pout, const float* __restrict__ inw,
    const float* __restrict__ inb, float* __restrict__ scsh)
{
  int bc = blockIdx.x, tid = threadIdx.x, c = bc & 127;
  float s = 0.f, s2 = 0.f;
#pragma unroll
  for (int i = 0; i < 9; i++) {
    size_t base = (size_t)bc * NPIX1 + tid + i * 256;
    float x = pout[base];
#pragma unroll
    for (int k = 1; k < NS; k++) x += pout[(size_t)k * B * CO * NPIX1 + base];
    s += x; s2 += x * x;
  }
#pragma unroll
  for (int off = 32; off > 0; off >>= 1) {
    s  += __shfl_down(s, off);
    s2 += __shfl_down(s2, off);
  }
  __shared__ float rs[4], rs2[4];
  int wid = tid >> 6, lane = tid & 63;
  if (lane == 0) { rs[wid] = s; rs2[wid] = s2; }
  __syncthreads();
  if (tid == 0) {
    float S  = rs[0] + rs[1] + rs[2] + rs[3];
    float S2 = rs2[0] + rs2[1] + rs2[2] + rs2[3];
    float mean = S * (1.f / NPIX1);
    float var  = S2 * (1.f / NPIX1) - mean * mean;
    float inv  = rsqrtf(var + 1e-5f);
    float sc = inw[c] * inv;
    scsh[2 * bc]     = sc;
    scsh[2 * bc + 1] = inb[c] - mean * sc;
  }
}

// ---------------- apply IN+PReLU on partial sums, write NHWC bf16 (transpose) ----------------
__global__ __launch_bounds__(256) void in_apply_hwc_kernel(
    const float* __restrict__ pout, const float* __restrict__ scsh,
    const float* __restrict__ alpha_p, ushort* __restrict__ outh)
{
  int blk = blockIdx.x;
  int cg = blk & 3;
  int pc = (blk >> 2) % 36;
  int b  = blk / (4 * 36);
  int c0 = cg * 32, pix0 = pc * 64;
  int tid = threadIdx.x;
  float a = *alpha_p;
  __shared__ float lt[32][65];
#pragma unroll
  for (int r = 0; r < 8; r++) {
    int c_l = r * 4 + (tid >> 6), px = tid & 63;
    size_t base = ((size_t)b * CO + c0 + c_l) * NPIX1 + pix0 + px;
    float x = pout[base];
#pragma unroll
    for (int k = 1; k < NS; k++) x += pout[(size_t)k * B * CO * NPIX1 + base];
    float sc = scsh[2 * (b * CO + c0 + c_l)];
    float sh = scsh[2 * (b * CO + c0 + c_l) + 1];
    float o = x * sc + sh;
    lt[c_l][px] = (o >= 0.f) ? o : a * o;
  }
  __syncthreads();
  int c_l = tid & 31;
#pragma unroll
  for (int r = 0; r < 8; r++) {
    int px = r * 8 + (tid >> 5);
    outh[((size_t)b * NPIX1 + pix0 + px) * CO + c0 + c_l] = f2bf(lt[c_l][px]);
  }
}

// ---------------- reduce partials + bias + IN + PReLU -> NCHW f32 (for conv2) ----------------
__global__ __launch_bounds__(256) void reduce_in_prelu_kernel(
    const float* __restrict__ pout, const float* __restrict__ cbias,
    const float* __restrict__ inw, const float* __restrict__ inb,
    const float* __restrict__ alpha_p, float* __restrict__ outf)
{
  int bc = blockIdx.x, tid = threadIdx.x, c = bc & 127;
  float bia = cbias[c];
  float v[9];
  float s = 0.f, s2 = 0.f;
#pragma unroll
  for (int i = 0; i < 9; i++) {
    size_t base = (size_t)bc * NPIX1 + tid + i * 256;
    float x = pout[base];
#pragma unroll
    for (int k = 1; k < NS; k++) x += pout[(size_t)k * B * CO * NPIX1 + base];
    x += bia;
    v[i] = x; s += x; s2 += x * x;
  }
#pragma unroll
  for (int off = 32; off > 0; off >>= 1) {
    s  += __shfl_down(s, off);
    s2 += __shfl_down(s2, off);
  }
  __shared__ float rs[4], rs2[4];
  int wid = tid >> 6, lane = tid & 63;
  if (lane == 0) { rs[wid] = s; rs2[wid] = s2; }
  __syncthreads();
  float S  = rs[0] + rs[1] + rs[2] + rs[3];
  float S2 = rs2[0] + rs2[1] + rs2[2] + rs2[3];
  float mean = S * (1.f / NPIX1);
  float var  = S2 * (1.f / NPIX1) - mean * mean;
  float inv  = rsqrtf(var + 1e-5f);
  float sc = inw[c] * inv;
  float sh = inb[c] - mean * sc;
  float a = *alpha_p;
  float* op = outf + (size_t)bc * NPIX1;
#pragma unroll
  for (int i = 0; i < 9; i++) {
    float o = v[i] * sc + sh;
    op[tid + i * 256] = (o >= 0.f) ? o : a * o;
  }
}

// ---------------- 1x1 conv (OCB oc/block), optional accumulate ----------------
template<int CI, int OCB, bool ADD>
__global__ __launch_bounds__(256) void conv1x1_kernel(
    const float* __restrict__ in, const float* __restrict__ wgt,
    const float* __restrict__ bias, float* __restrict__ out, int npix)
{
  int nchunk = npix >> 8;
  int blk = blockIdx.x;
  int chunk = blk % nchunk;
  int og = (blk / nchunk) % (CO / OCB);
  int b  = blk / (nchunk * (CO / OCB));
  int pix = chunk * 256 + threadIdx.x;
  const float* ip = in + (size_t)b * CI * npix + pix;
  int o0 = og * OCB;
  const float* wp = wgt + (size_t)o0 * CI;
  float a[OCB];
#pragma unroll
  for (int o = 0; o < OCB; o++) a[o] = 0.f;
  for (int ci = 0; ci < CI; ci++) {
    float xv = ip[(size_t)ci * npix];
#pragma unroll
    for (int o = 0; o < OCB; o++) a[o] += wp[(size_t)o * CI + ci] * xv;
  }
  float* op = out + ((size_t)b * CO + o0) * npix + pix;
#pragma unroll
  for (int o = 0; o < OCB; o++) {
    if (ADD) op[(size_t)o * npix] += a[o] + bias[o0 + o];
    else     op[(size_t)o * npix]  = a[o] + bias[o0 + o];
  }
}

// ---------------- bicubic taps (align_corners=False, a=-0.75, scale 2) ----------------
__device__ inline void bicubic_taps(int i, int n, int* r, float* w)
{
  const float we[4] = {-0.03515625f, 0.26171875f, 0.87890625f, -0.10546875f};
  bool odd = (i & 1);
  int base = (i >> 1) + (odd ? 0 : -1);
#pragma unroll
  for (int q = 0; q < 4; q++) {
    int rr = base + q - 1;
    r[q] = rr < 0 ? 0 : (rr > n - 1 ? n - 1 : rr);
    w[q] = odd ? we[3 - q] : we[q];
  }
}

// ---------------- 2x bicubic upsample, NCHW f32 -> NHWC bf16 via LDS ----------------
__global__ __launch_bounds__(256) void upsample_t_kernel(
    const float* __restrict__ in, ushort* __restrict__ outh)
{
  int blk = blockIdx.x;
  int cg = blk & 3;
  int i  = (blk >> 2) % H2;
  int b  = blk / (4 * H2);
  int c0 = cg * 32;
  int tid = threadIdx.x;

  int rh[4]; float wh[4];
  bicubic_taps(i, H, rh, wh);

  __shared__ float ls[4 * 48 * 33];   // [a][ww][c] padded
  for (int k = 0; k < 24; k++) {
    int q = tid + k * 256;            // 6144 elements
    int ww = q % 48;
    int a  = (q / 48) & 3;
    int c_l = q / 192;
    ls[(a * 48 + ww) * 33 + c_l] =
        in[((size_t)b * CO + c0 + c_l) * NPIX1 + rh[a] * W + ww];
  }
  __syncthreads();

  int c_l = tid & 31;
#pragma unroll
  for (int rep = 0; rep < 12; rep++) {
    int j = rep * 8 + (tid >> 5);
    int rwj[4]; float wwj[4];
    bicubic_taps(j, W, rwj, wwj);
    float s = 0.f;
#pragma unroll
    for (int a = 0; a < 4; a++) {
      float r = 0.f;
#pragma unroll
      for (int q = 0; q < 4; q++)
        r += wwj[q] * ls[(a * 48 + rwj[q]) * 33 + c_l];
      s += wh[a] * r;
    }
    outh[((size_t)(b * H2 + i) * W2 + j) * CO + c0 + c_l] = f2bf(s);
  }
}

// ---------------- pac_w f32 [o][c][p] -> bf16 [p][o][c] ----------------
__global__ __launch_bounds__(256) void wconv_kernel(
    const float* __restrict__ pw, ushort* __restrict__ wbo)
{
  int idx = blockIdx.x * 256 + threadIdx.x;  // < 25*128*128
  int c = idx & 127;
  int o = (idx >> 7) & 127;
  int p = idx >> 14;
  wbo[idx] = f2bf(pw[((size_t)o * CO + c) * 25 + p]);
}

// ---------------- PAC guidance d2 partial (split over c) ----------------
__global__ __launch_bounds__(256) void pac_kern_part_kernel(
    const float* __restrict__ g, float* __restrict__ pd2)
{
  int blk = blockIdx.x;
  int s = blk & 3;
  int tile = (blk >> 2) % 36;
  int b = blk / (4 * 36);
  int ty = tile / 6, tx = tile % 6;
  int h0 = ty * 16, w0 = tx * 16;
  int tid = threadIdx.x, px = tid & 15, py = tid >> 4;
  __shared__ float gt[20 * 24];
  float d2[25];
#pragma unroll
  for (int p = 0; p < 25; p++) d2[p] = 0.f;

  for (int c = s * 32; c < s * 32 + 32; c++) {
    const float* gp = g + ((size_t)b * CO + c) * NPIX2;
    for (int idx = tid; idx < 400; idx += 256) {
      int rh = idx / 20, rw = idx - rh * 20;
      int hh = h0 - 2 + rh, ww = w0 - 2 + rw;
      gt[rh * 24 + rw] = (hh >= 0 && hh < H2 && ww >= 0 && ww < W2) ? gp[hh * W2 + ww] : 0.f;
    }
    __syncthreads();
    float ctr = gt[(py + 2) * 24 + px + 2];
#pragma unroll
    for (int dy = 0; dy < 5; dy++)
#pragma unroll
      for (int dx = 0; dx < 5; dx++) {
        float d = gt[(py + dy) * 24 + px + dx] - ctr;
        d2[dy * 5 + dx] += d * d;
      }
    __syncthreads();
  }
  float* op = pd2 + ((size_t)((b * 36 + tile) * 4 + s) * 25) * 256 + tid;
#pragma unroll
  for (int p = 0; p < 25; p++) op[(size_t)p * 256] = d2[p];
}

// ---------------- finalize: sum splits, exp, normalize -> kern [b][pix][32] ----------------
__global__ __launch_bounds__(256) void pac_kern_fin_kernel(
    const float* __restrict__ pd2, float* __restrict__ kern)
{
  int blk = blockIdx.x;
  int tile = blk % 36, b = blk / 36;
  int ty = tile / 6, tx = tile % 6;
  int h0 = ty * 16, w0 = tx * 16;
  int tid = threadIdx.x, px = tid & 15, py = tid >> 4;
  const float* ip = pd2 + ((size_t)(b * 36 + tile) * 4 * 25) * 256 + tid;
  float e[25];
  float sum = 0.f;
#pragma unroll
  for (int p = 0; p < 25; p++) {
    float d = 0.f;
#pragma unroll
    for (int s = 0; s < 4; s++) d += ip[(size_t)(s * 25 + p) * 256];
    e[p] = __expf(-0.5f * d);
    sum += e[p];
  }
  float inv = 1.f / sum;
  int pixg = (h0 + py) * W2 + w0 + px;
  float* op = kern + ((size_t)b * NPIX2 + pixg) * 32;
#pragma unroll
  for (int p = 0; p < 25; p++) op[p] = e[p] * inv;
}

// ---------------- PAC conv via MFMA ----------------
// tile = 4 rows x 16 cols, 128 o; 8 waves: wv&3 -> o-split (32 o), wv>>2 -> row pair
// grid: B * (H2/4) * (W2/16) = 288
__global__ __launch_bounds__(512, 2) void pac_mfma_kernel(
    const ushort* __restrict__ xh,    // NHWC bf16 [b][96][96][128]
    const float* __restrict__ kern,   // [b][9216][32]
    const ushort* __restrict__ wb,    // bf16 [25][128][128]
    const float* __restrict__ bias, float* __restrict__ out)
{
  int blk = blockIdx.x;
  int tw = blk % 6;
  int th = (blk / 6) % 24;
  int b  = blk / (6 * 24);
  int h0 = th * 4, w0 = tw * 16;
  int tid = threadIdx.x, lane = tid & 63, wv = tid >> 6;  // 0..7
  int l15 = lane & 15, l4 = (lane >> 4) & 3;
  int ow  = wv & 3;          // o-split
  int rh0 = (wv >> 2) * 2;   // rows rh0, rh0+1 of the 4-row tile

  __shared__ ushort xt[160 * 128];  // 8 halo rows x 20 cols
  __shared__ float kt[64][33];

  for (int q = tid; q < 2560; q += 512) {
    int pixi = q >> 4, cb = q & 15;
    int rh = pixi / 20, rw = pixi - rh * 20;
    int hg = h0 - 2 + rh, wg = w0 - 2 + rw;
    uint4 v{0u, 0u, 0u, 0u};
    if (hg >= 0 && hg < H2 && wg >= 0 && wg < W2)
      v = *(const uint4*)(xh + ((((size_t)b * H2 + hg) * W2 + wg) << 7) + (cb << 3));
    *(uint4*)(xt + (pixi << 7) + ((cb ^ (pixi & 15)) << 3)) = v;
  }
  {
    int pixl = tid >> 3, poff = (tid & 7) << 2;   // 64 px x 8 groups = 512
    int r = pixl >> 4, col = pixl & 15;
    const float* kp = kern + ((size_t)b * NPIX2 + (h0 + r) * W2 + w0 + col) * 32 + poff;
    float4 kv = *(const float4*)kp;
    kt[pixl][poff] = kv.x; kt[pixl][poff + 1] = kv.y;
    kt[pixl][poff + 2] = kv.z; kt[pixl][poff + 3] = kv.w;
  }
  __syncthreads();

  int wo = ow * 32;
  const ushort* wbase = wb + (size_t)(wo + l15) * CO + l4 * 8;

  f32x4 acc0[2], acc1[2];
#pragma unroll
  for (int nf = 0; nf < 2; nf++) {
    acc0[nf] = {0.f, 0.f, 0.f, 0.f};
    acc1[nf] = {0.f, 0.f, 0.f, 0.f};
  }

  bf16x8 aC0[4], aC1[4], aN0[4], aN1[4];
#pragma unroll
  for (int kc = 0; kc < 4; kc++) {
    aC0[kc] = *(const bf16x8*)(wbase + kc * 32);
    aC1[kc] = *(const bf16x8*)(wbase + 16 * CO + kc * 32);
  }

  int dy = 0, dx = 0;
#pragma unroll 1
  for (int p = 0; p < 25; ++p) {
    if (p < 24) {
      const ushort* wnext = wbase + (size_t)(p + 1) * CO * CO;
#pragma unroll
      for (int kc = 0; kc < 4; kc++) {
        aN0[kc] = *(const bf16x8*)(wnext + kc * 32);
        aN1[kc] = *(const bf16x8*)(wnext + 16 * CO + kc * 32);
      }
    }
#pragma unroll
    for (int nf = 0; nf < 2; nf++) {
      int row = rh0 + nf;
      int pix = (row + dy) * 20 + dx + l15;
      int base = pix << 7;
      int sw = pix & 15;
      f32x4 y0 = {0.f, 0.f, 0.f, 0.f};
      f32x4 y1 = {0.f, 0.f, 0.f, 0.f};
#pragma unroll
      for (int kc = 0; kc < 4; kc++) {
        bf16x8 bb = *(const bf16x8*)(xt + base + (((kc * 4 + l4) ^ sw) << 3));
        y0 = __builtin_amdgcn_mfma_f32_16x16x32_bf16(aC0[kc], bb, y0, 0, 0, 0);
        y1 = __builtin_amdgcn_mfma_f32_16x16x32_bf16(aC1[kc], bb, y1, 0, 0, 0);
      }
      float ks = kt[(row << 4) + l15][p];
#pragma unroll
      for (int r = 0; r < 4; r++) {
        acc0[nf][r] += ks * y0[r];
        acc1[nf][r] += ks * y1[r];
      }
    }
#pragma unroll
    for (int kc = 0; kc < 4; kc++) { aC0[kc] = aN0[kc]; aC1[kc] = aN1[kc]; }
    if (++dx == 5) { dx = 0; dy++; }
  }

#pragma unroll
  for (int nf = 0; nf < 2; nf++) {
    int row = rh0 + nf;
    int gpix = (h0 + row) * W2 + w0 + l15;
#pragma unroll
    for (int r = 0; r < 4; r++) {
      int o = wo + l4 * 4 + r;
      out[((size_t)b * CO + o) * NPIX2 + gpix] = acc0[nf][r] + bias[o];
      out[((size_t)b * CO + o + 16) * NPIX2 + gpix] = acc1[nf][r] + bias[o + 16];
    }
  }
}

extern "C" void kernel_launch(void* const* d_in, const int* in_sizes, int n_in,
                              void* d_out, int out_size, void* d_ws, size_t ws_size,
                              hipStream_t stream)
{
  (void)in_sizes; (void)n_in; (void)out_size; (void)ws_size;
  const float* input    = (const float*)d_in[0];
  const float* feature  = (const float*)d_in[1];
  const float* conv1_w  = (const float*)d_in[2];
  const float* conv1_b  = (const float*)d_in[3];
  const float* in1_w    = (const float*)d_in[4];
  const float* in1_b    = (const float*)d_in[5];
  const float* prelu1_a = (const float*)d_in[6];
  const float* conv2_w  = (const float*)d_in[7];
  const float* conv2_b  = (const float*)d_in[8];
  const float* in2_w    = (const float*)d_in[9];
  const float* in2_b    = (const float*)d_in[10];
  const float* prelu2_a = (const float*)d_in[11];
  const float* res_w    = (const float*)d_in[12];
  const float* res_b    = (const float*)d_in[13];
  const float* feat_w   = (const float*)d_in[14];
  const float* feat_b   = (const float*)d_in[15];
  const float* pac_w    = (const float*)d_in[16];
  const float* pac_b    = (const float*)d_in[17];
  float* out = (float*)d_out;

  // workspace layout (f32 element offsets); aliases have disjoint lifetimes
  float* ws = (float*)d_ws;
  float*  kern = ws;                              // [0, 589824)  late: kernfin->pacmfma
  ushort* t1h  = (ushort*)ws;                     // alias: apply1->conv2 (294912 f)
  ushort* wt2  = (ushort*)(ws + 294912);          // wt2k->conv2 (73728 f)
  ushort* wt1  = (ushort*)(ws + 368640);          // wt1k->conv1 (147456 f)
  float*  t2   = ws + 589824;                     // 589824
  float*  pws  = ws + 1179648;                    // 2359296 (conv partials / pd2)
  float*  g    = ws + 3538944;                    // 2359296 (featconv->kernpart)
  ushort* xinh = (ushort*)g;                      // alias: cvt_in->conv1 (589824 f)
  ushort* yh   = (ushort*)(ws + 5898240);         // 2359296 ushort
  ushort* wbb  = (ushort*)(ws + 7077888);         // 409600 ushort
  float*  scsh = ws + 7282688;                    // 512 f (end 7283200 f = 29.1MB)
  float*  pd2  = pws;

  // weight/input transforms
  wconv_kernel<<<1600, 256, 0, stream>>>(pac_w, wbb);
  cvt_in_t_kernel<<<B * 36 * 8, 256, 0, stream>>>(input, xinh);
  wtconv_kernel<CIN, 8><<<(9 * 128 * CIN) / 256, 256, 0, stream>>>(conv1_w, wt1);
  wtconv_kernel<CO, 7><<<(9 * 128 * CO) / 256, 256, 0, stream>>>(conv2_w, wt2);

  // conv1 (MFMA) -> IN stats -> apply+PReLU -> NHWC bf16 t1h
  conv3_mfma_kernel<CIN><<<B * NS * 36, 256, 0, stream>>>(xinh, wt1, pws);
  in_stats_kernel<<<B * CO, 256, 0, stream>>>(pws, in1_w, in1_b, scsh);
  in_apply_hwc_kernel<<<B * 36 * 4, 256, 0, stream>>>(pws, scsh, prelu1_a, t1h);
  // conv2 (MFMA) -> reduce+IN2+PReLU -> NCHW f32 t2
  conv3_mfma_kernel<CO><<<B * NS * 36, 256, 0, stream>>>(t1h, wt2, pws);
  reduce_in_prelu_kernel<<<B * CO, 256, 0, stream>>>(
      pws, conv2_b, in2_w, in2_b, prelu2_a, t2);
  // residual 1x1 accumulate into t2 (f32 NCHW)
  conv1x1_kernel<CIN, 4, true><<<B * (CO / 4) * (NPIX1 / 256), 256, 0, stream>>>(
      input, res_w, res_b, t2, NPIX1);
  // bicubic 2x upsample -> NHWC bf16 (LDS transpose)
  upsample_t_kernel<<<B * H2 * 4, 256, 0, stream>>>(t2, yh);
  // guidance g = 1x1(feature), f32 NCHW
  conv1x1_kernel<CO, 8, false><<<B * (CO / 8) * (NPIX2 / 256), 256, 0, stream>>>(
      feature, feat_w, feat_b, g, NPIX2);
  // gaussian kernel
  pac_kern_part_kernel<<<B * 36 * 4, 256, 0, stream>>>(g, pd2);
  pac_kern_fin_kernel<<<B * 36, 256, 0, stream>>>(pd2, kern);
  // PAC conv on matrix cores
  pac_mfma_kernel<<<B * 24 * 6, 512, 0, stream>>>(yh, kern, wbb, pac_b, out);
}

// Round 8
// 181.579 us; speedup vs baseline: 1.3078x; 1.3078x over previous
//
#include <hip/hip_runtime.h>
#include <hip/hip_bf16.h>

typedef __attribute__((ext_vector_type(8))) short bf16x8;
typedef __attribute__((ext_vector_type(4))) float f32x4;

constexpr int B   = 2;
constexpr int CIN = 256;
constexpr int CO  = 128;
constexpr int H = 48, W = 48;
constexpr int H2 = 96, W2 = 96;
constexpr int NPIX1 = H * W;    // 2304
constexpr int NPIX2 = H2 * W2;  // 9216
constexpr int NS = 4;           // conv split-K factor

__device__ inline ushort f2bf(float v)
{
  __hip_bfloat16 h = __float2bfloat16(v);
  return *reinterpret_cast<ushort*>(&h);
}

// ---------------- input NCHW f32 -> NHWC bf16, LDS-tiled transpose ----------------
__global__ __launch_bounds__(256) void cvt_in_t_kernel(
    const float* __restrict__ in, ushort* __restrict__ outh)
{
  int blk = blockIdx.x;
  int cg = blk & 7;
  int pc = (blk >> 3) % 36;
  int b  = blk / (8 * 36);
  int c0 = cg * 32, pix0 = pc * 64;
  int tid = threadIdx.x;
  __shared__ float lt[32][65];
#pragma unroll
  for (int r = 0; r < 8; r++) {
    int c_l = r * 4 + (tid >> 6), px = tid & 63;
    lt[c_l][px] = in[((size_t)b * CIN + c0 + c_l) * NPIX1 + pix0 + px];
  }
  __syncthreads();
  int c_l = tid & 31;
#pragma unroll
  for (int r = 0; r < 8; r++) {
    int px = r * 8 + (tid >> 5);
    outh[((size_t)b * NPIX1 + pix0 + px) * CIN + c0 + c_l] = f2bf(lt[c_l][px]);
  }
}

// ---------------- conv weight f32 [o][ci][3][3] -> bf16 [tap][o][ci] ----------------
template<int CIg, int SH>
__global__ __launch_bounds__(256) void wtconv_kernel(
    const float* __restrict__ w, ushort* __restrict__ wt)
{
  int idx = blockIdx.x * 256 + threadIdx.x;   // 9*128*CIg
  int ci = idx & (CIg - 1);
  int o  = (idx >> SH) & 127;
  int tap = idx >> (SH + 7);
  wt[idx] = f2bf(w[((size_t)o * CIg + ci) * 9 + tap]);
}

// ---------------- conv3x3 via MFMA (implicit GEMM, split-K over ci) ----------------
template<int CIg>
__global__ __launch_bounds__(256, 4) void conv3_mfma_kernel(
    const ushort* __restrict__ xh,   // NHWC bf16 [b][48][48][CIg]
    const ushort* __restrict__ wt,   // bf16 [9][128][CIg]
    float* __restrict__ pout)        // [NS][b][128][2304]
{
  constexpr int CS = CIg / NS;
  constexpr int G  = CS / 8;
  constexpr int KC = CS / 32;
  int blk = blockIdx.x;
  int tile = blk % 36;
  int s = (blk / 36) & 3;
  int b = blk / 144;
  int th = tile / 3, tw = tile % 3;
  int h0 = th * 4, w0 = tw * 16;
  int tid = threadIdx.x, lane = tid & 63, wv = tid >> 6;
  int l15 = lane & 15, l4 = (lane >> 4) & 3;

  __shared__ ushort xt[108 * CS];
  for (int q = tid; q < 108 * G; q += 256) {
    int pixi = q / G, g = q & (G - 1);
    int rh = pixi / 18, rw = pixi - rh * 18;
    int hg = h0 - 1 + rh, wg = w0 - 1 + rw;
    uint4 v{0u, 0u, 0u, 0u};
    if (hg >= 0 && hg < H && wg >= 0 && wg < W)
      v = *(const uint4*)(xh + (size_t)(b * NPIX1 + hg * W + wg) * CIg + s * CS + g * 8);
    *(uint4*)(xt + pixi * CS + ((g ^ (pixi & (G - 1))) * 8)) = v;
  }
  __syncthreads();

  int wo = wv * 32;
  const ushort* wbase = wt + (size_t)(wo + l15) * CIg + s * CS + l4 * 8;

  f32x4 acc0[4], acc1[4];
#pragma unroll
  for (int nf = 0; nf < 4; nf++) {
    acc0[nf] = {0.f, 0.f, 0.f, 0.f};
    acc1[nf] = {0.f, 0.f, 0.f, 0.f};
  }

  bf16x8 aC0[KC], aC1[KC], aN0[KC], aN1[KC];
#pragma unroll
  for (int kc = 0; kc < KC; kc++) {
    aC0[kc] = *(const bf16x8*)(wbase + kc * 32);
    aC1[kc] = *(const bf16x8*)(wbase + 16 * CIg + kc * 32);
  }

#pragma unroll 1
  for (int tap = 0; tap < 9; ++tap) {
    if (tap < 8) {
      const ushort* wn = wbase + (size_t)(tap + 1) * 128 * CIg;
#pragma unroll
      for (int kc = 0; kc < KC; kc++) {
        aN0[kc] = *(const bf16x8*)(wn + kc * 32);
        aN1[kc] = *(const bf16x8*)(wn + 16 * CIg + kc * 32);
      }
    }
    int kh = (tap >= 6) ? 2 : ((tap >= 3) ? 1 : 0);
    int kw = tap - kh * 3;
#pragma unroll
    for (int kc = 0; kc < KC; kc++) {
#pragma unroll
      for (int nf = 0; nf < 4; nf++) {
        int pix = (nf + kh) * 18 + kw + l15;
        bf16x8 bb = *(const bf16x8*)(xt + pix * CS + (((kc * 4 + l4) ^ (pix & (G - 1))) * 8));
        acc0[nf] = __builtin_amdgcn_mfma_f32_16x16x32_bf16(aC0[kc], bb, acc0[nf], 0, 0, 0);
        acc1[nf] = __builtin_amdgcn_mfma_f32_16x16x32_bf16(aC1[kc], bb, acc1[nf], 0, 0, 0);
      }
    }
#pragma unroll
    for (int kc = 0; kc < KC; kc++) { aC0[kc] = aN0[kc]; aC1[kc] = aN1[kc]; }
  }

#pragma unroll
  for (int nf = 0; nf < 4; nf++) {
    int pixg = (h0 + nf) * W + w0 + l15;
#pragma unroll
    for (int r = 0; r < 4; r++) {
      int o = wo + l4 * 4 + r;
      pout[((size_t)(s * B + b) * CO + o) * NPIX1 + pixg] = acc0[nf][r];
      pout[((size_t)(s * B + b) * CO + o + 16) * NPIX1 + pixg] = acc1[nf][r];
    }
  }
}

// ---------------- instance-norm stats from partials -> scale/shift ----------------
__global__ __launch_bounds__(256) void in_stats_kernel(
    const float* __restrict__ pout, const float* __restrict__ inw,
    const float* __restrict__ inb, float* __restrict__ scsh)
{
  int bc = blockIdx.x, tid = threadIdx.x, c = bc & 127;
  float s = 0.f, s2 = 0.f;
#pragma unroll
  for (int i = 0; i < 9; i++) {
    size_t base = (size_t)bc * NPIX1 + tid + i * 256;
    float x = pout[base];
#pragma unroll
    for (int k = 1; k < NS; k++) x += pout[(size_t)k * B * CO * NPIX1 + base];
    s += x; s2 += x * x;
  }
#pragma unroll
  for (int off = 32; off > 0; off >>= 1) {
    s  += __shfl_down(s, off);
    s2 += __shfl_down(s2, off);
  }
  __shared__ float rs[4], rs2[4];
  int wid = tid >> 6, lane = tid & 63;
  if (lane == 0) { rs[wid] = s; rs2[wid] = s2; }
  __syncthreads();
  if (tid == 0) {
    float S  = rs[0] + rs[1] + rs[2] + rs[3];
    float S2 = rs2[0] + rs2[1] + rs2[2] + rs2[3];
    float mean = S * (1.f / NPIX1);
    float var  = S2 * (1.f / NPIX1) - mean * mean;
    float inv  = rsqrtf(var + 1e-5f);
    float sc = inw[c] * inv;
    scsh[2 * bc]     = sc;
    scsh[2 * bc + 1] = inb[c] - mean * sc;
  }
}

// ---------------- apply IN+PReLU on partial sums, write NHWC bf16 (transpose) ----------------
__global__ __launch_bounds__(256) void in_apply_hwc_kernel(
    const float* __restrict__ pout, const float* __restrict__ scsh,
    const float* __restrict__ alpha_p, ushort* __restrict__ outh)
{
  int blk = blockIdx.x;
  int cg = blk & 3;
  int pc = (blk >> 2) % 36;
  int b  = blk / (4 * 36);
  int c0 = cg * 32, pix0 = pc * 64;
  int tid = threadIdx.x;
  float a = *alpha_p;
  __shared__ float lt[32][65];
#pragma unroll
  for (int r = 0; r < 8; r++) {
    int c_l = r * 4 + (tid >> 6), px = tid & 63;
    size_t base = ((size_t)b * CO + c0 + c_l) * NPIX1 + pix0 + px;
    float x = pout[base];
#pragma unroll
    for (int k = 1; k < NS; k++) x += pout[(size_t)k * B * CO * NPIX1 + base];
    float sc = scsh[2 * (b * CO + c0 + c_l)];
    float sh = scsh[2 * (b * CO + c0 + c_l) + 1];
    float o = x * sc + sh;
    lt[c_l][px] = (o >= 0.f) ? o : a * o;
  }
  __syncthreads();
  int c_l = tid & 31;
#pragma unroll
  for (int r = 0; r < 8; r++) {
    int px = r * 8 + (tid >> 5);
    outh[((size_t)b * NPIX1 + pix0 + px) * CO + c0 + c_l] = f2bf(lt[c_l][px]);
  }
}

// ---------------- reduce partials + bias + IN + PReLU -> NCHW f32 (for conv2) ----------------
__global__ __launch_bounds__(256) void reduce_in_prelu_kernel(
    const float* __restrict__ pout, const float* __restrict__ cbias,
    const float* __restrict__ inw, const float* __restrict__ inb,
    const float* __restrict__ alpha_p, float* __restrict__ outf)
{
  int bc = blockIdx.x, tid = threadIdx.x, c = bc & 127;
  float bia = cbias[c];
  float v[9];
  float s = 0.f, s2 = 0.f;
#pragma unroll
  for (int i = 0; i < 9; i++) {
    size_t base = (size_t)bc * NPIX1 + tid + i * 256;
    float x = pout[base];
#pragma unroll
    for (int k = 1; k < NS; k++) x += pout[(size_t)k * B * CO * NPIX1 + base];
    x += bia;
    v[i] = x; s += x; s2 += x * x;
  }
#pragma unroll
  for (int off = 32; off > 0; off >>= 1) {
    s  += __shfl_down(s, off);
    s2 += __shfl_down(s2, off);
  }
  __shared__ float rs[4], rs2[4];
  int wid = tid >> 6, lane = tid & 63;
  if (lane == 0) { rs[wid] = s; rs2[wid] = s2; }
  __syncthreads();
  float S  = rs[0] + rs[1] + rs[2] + rs[3];
  float S2 = rs2[0] + rs2[1] + rs2[2] + rs2[3];
  float mean = S * (1.f / NPIX1);
  float var  = S2 * (1.f / NPIX1) - mean * mean;
  float inv  = rsqrtf(var + 1e-5f);
  float sc = inw[c] * inv;
  float sh = inb[c] - mean * sc;
  float a = *alpha_p;
  float* op = outf + (size_t)bc * NPIX1;
#pragma unroll
  for (int i = 0; i < 9; i++) {
    float o = v[i] * sc + sh;
    op[tid + i * 256] = (o >= 0.f) ? o : a * o;
  }
}

// ---------------- 1x1 conv (OCB oc/block), optional accumulate ----------------
template<int CI, int OCB, bool ADD>
__global__ __launch_bounds__(256) void conv1x1_kernel(
    const float* __restrict__ in, const float* __restrict__ wgt,
    const float* __restrict__ bias, float* __restrict__ out, int npix)
{
  int nchunk = npix >> 8;
  int blk = blockIdx.x;
  int chunk = blk % nchunk;
  int og = (blk / nchunk) % (CO / OCB);
  int b  = blk / (nchunk * (CO / OCB));
  int pix = chunk * 256 + threadIdx.x;
  const float* ip = in + (size_t)b * CI * npix + pix;
  int o0 = og * OCB;
  const float* wp = wgt + (size_t)o0 * CI;
  float a[OCB];
#pragma unroll
  for (int o = 0; o < OCB; o++) a[o] = 0.f;
  for (int ci = 0; ci < CI; ci++) {
    float xv = ip[(size_t)ci * npix];
#pragma unroll
    for (int o = 0; o < OCB; o++) a[o] += wp[(size_t)o * CI + ci] * xv;
  }
  float* op = out + ((size_t)b * CO + o0) * npix + pix;
#pragma unroll
  for (int o = 0; o < OCB; o++) {
    if (ADD) op[(size_t)o * npix] += a[o] + bias[o0 + o];
    else     op[(size_t)o * npix]  = a[o] + bias[o0 + o];
  }
}

// ---------------- bicubic taps (align_corners=False, a=-0.75, scale 2) ----------------
__device__ inline void bicubic_taps(int i, int n, int* r, float* w)
{
  const float we[4] = {-0.03515625f, 0.26171875f, 0.87890625f, -0.10546875f};
  bool odd = (i & 1);
  int base = (i >> 1) + (odd ? 0 : -1);
#pragma unroll
  for (int q = 0; q < 4; q++) {
    int rr = base + q - 1;
    r[q] = rr < 0 ? 0 : (rr > n - 1 ? n - 1 : rr);
    w[q] = odd ? we[3 - q] : we[q];
  }
}

// ---------------- 2x bicubic upsample, NCHW f32 -> NHWC bf16 via LDS ----------------
__global__ __launch_bounds__(256) void upsample_t_kernel(
    const float* __restrict__ in, ushort* __restrict__ outh)
{
  int blk = blockIdx.x;
  int cg = blk & 3;
  int i  = (blk >> 2) % H2;
  int b  = blk / (4 * H2);
  int c0 = cg * 32;
  int tid = threadIdx.x;

  int rh[4]; float wh[4];
  bicubic_taps(i, H, rh, wh);

  __shared__ float ls[4 * 48 * 33];   // [a][ww][c] padded
  for (int k = 0; k < 24; k++) {
    int q = tid + k * 256;            // 6144 elements
    int ww = q % 48;
    int a  = (q / 48) & 3;
    int c_l = q / 192;
    ls[(a * 48 + ww) * 33 + c_l] =
        in[((size_t)b * CO + c0 + c_l) * NPIX1 + rh[a] * W + ww];
  }
  __syncthreads();

  int c_l = tid & 31;
#pragma unroll
  for (int rep = 0; rep < 12; rep++) {
    int j = rep * 8 + (tid >> 5);
    int rwj[4]; float wwj[4];
    bicubic_taps(j, W, rwj, wwj);
    float s = 0.f;
#pragma unroll
    for (int a = 0; a < 4; a++) {
      float r = 0.f;
#pragma unroll
      for (int q = 0; q < 4; q++)
        r += wwj[q] * ls[(a * 48 + rwj[q]) * 33 + c_l];
      s += wh[a] * r;
    }
    outh[((size_t)(b * H2 + i) * W2 + j) * CO + c0 + c_l] = f2bf(s);
  }
}

// ---------------- pac_w f32 [o][c][p] -> bf16 [p][o][c] ----------------
__global__ __launch_bounds__(256) void wconv_kernel(
    const float* __restrict__ pw, ushort* __restrict__ wbo)
{
  int idx = blockIdx.x * 256 + threadIdx.x;  // < 25*128*128
  int c = idx & 127;
  int o = (idx >> 7) & 127;
  int p = idx >> 14;
  wbo[idx] = f2bf(pw[((size_t)o * CO + c) * 25 + p]);
}

// ---------------- PAC guidance d2 partial (split over c) ----------------
__global__ __launch_bounds__(256) void pac_kern_part_kernel(
    const float* __restrict__ g, float* __restrict__ pd2)
{
  int blk = blockIdx.x;
  int s = blk & 3;
  int tile = (blk >> 2) % 36;
  int b = blk / (4 * 36);
  int ty = tile / 6, tx = tile % 6;
  int h0 = ty * 16, w0 = tx * 16;
  int tid = threadIdx.x, px = tid & 15, py = tid >> 4;
  __shared__ float gt[20 * 24];
  float d2[25];
#pragma unroll
  for (int p = 0; p < 25; p++) d2[p] = 0.f;

  for (int c = s * 32; c < s * 32 + 32; c++) {
    const float* gp = g + ((size_t)b * CO + c) * NPIX2;
    for (int idx = tid; idx < 400; idx += 256) {
      int rh = idx / 20, rw = idx - rh * 20;
      int hh = h0 - 2 + rh, ww = w0 - 2 + rw;
      gt[rh * 24 + rw] = (hh >= 0 && hh < H2 && ww >= 0 && ww < W2) ? gp[hh * W2 + ww] : 0.f;
    }
    __syncthreads();
    float ctr = gt[(py + 2) * 24 + px + 2];
#pragma unroll
    for (int dy = 0; dy < 5; dy++)
#pragma unroll
      for (int dx = 0; dx < 5; dx++) {
        float d = gt[(py + dy) * 24 + px + dx] - ctr;
        d2[dy * 5 + dx] += d * d;
      }
    __syncthreads();
  }
  float* op = pd2 + ((size_t)((b * 36 + tile) * 4 + s) * 25) * 256 + tid;
#pragma unroll
  for (int p = 0; p < 25; p++) op[(size_t)p * 256] = d2[p];
}

// ---------------- finalize: sum splits, exp, normalize -> kern [b][pix][32] ----------------
__global__ __launch_bounds__(256) void pac_kern_fin_kernel(
    const float* __restrict__ pd2, float* __restrict__ kern)
{
  int blk = blockIdx.x;
  int tile = blk % 36, b = blk / 36;
  int ty = tile / 6, tx = tile % 6;
  int h0 = ty * 16, w0 = tx * 16;
  int tid = threadIdx.x, px = tid & 15, py = tid >> 4;
  const float* ip = pd2 + ((size_t)(b * 36 + tile) * 4 * 25) * 256 + tid;
  float e[25];
  float sum = 0.f;
#pragma unroll
  for (int p = 0; p < 25; p++) {
    float d = 0.f;
#pragma unroll
    for (int s = 0; s < 4; s++) d += ip[(size_t)(s * 25 + p) * 256];
    e[p] = __expf(-0.5f * d);
    sum += e[p];
  }
  float inv = 1.f / sum;
  int pixg = (h0 + py) * W2 + w0 + px;
  float* op = kern + ((size_t)b * NPIX2 + pixg) * 32;
#pragma unroll
  for (int p = 0; p < 25; p++) op[p] = e[p] * inv;
}

// ---------------- PAC conv via MFMA ----------------
// tile = 8 rows x 16 cols, 64 o per block; 4 waves = o-split (16 o each, nf=8)
// grid: B * 12 * 6 * 2 = 288
__global__ __launch_bounds__(256, 2) void pac_mfma_kernel(
    const ushort* __restrict__ xh,    // NHWC bf16 [b][96][96][128]
    const float* __restrict__ kern,   // [b][9216][32]
    const ushort* __restrict__ wb,    // bf16 [25][128][128]
    const float* __restrict__ bias, float* __restrict__ out)
{
  int blk = blockIdx.x;
  int og = blk & 1;
  int tw = (blk >> 1) % 6;
  int th = (blk >> 1) / 6 % 12;
  int b  = blk / (2 * 6 * 12);
  int h0 = th * 8, w0 = tw * 16;
  int tid = threadIdx.x, lane = tid & 63, wv = tid >> 6;
  int l15 = lane & 15, l4 = (lane >> 4) & 3;

  __shared__ ushort xt[240 * 128];
  __shared__ float kt[128][33];

  for (int q = tid; q < 3840; q += 256) {
    int pixi = q >> 4, cb = q & 15;
    int rh = pixi / 20, rw = pixi - rh * 20;
    int hg = h0 - 2 + rh, wg = w0 - 2 + rw;
    uint4 v{0u, 0u, 0u, 0u};
    if (hg >= 0 && hg < H2 && wg >= 0 && wg < W2)
      v = *(const uint4*)(xh + ((((size_t)b * H2 + hg) * W2 + wg) << 7) + (cb << 3));
    *(uint4*)(xt + (pixi << 7) + ((cb ^ (pixi & 15)) << 3)) = v;
  }
  for (int q = tid; q < 1024; q += 256) {
    int pixl = q >> 3, poff = (q & 7) << 2;
    int r = pixl >> 4, col = pixl & 15;
    const float* kp = kern + ((size_t)b * NPIX2 + (h0 + r) * W2 + w0 + col) * 32 + poff;
    float4 kv = *(const float4*)kp;
    kt[pixl][poff] = kv.x; kt[pixl][poff + 1] = kv.y;
    kt[pixl][poff + 2] = kv.z; kt[pixl][poff + 3] = kv.w;
  }
  __syncthreads();

  int wo = og * 64 + wv * 16;     // this wave's 16 output channels
  const ushort* wbase = wb + (size_t)(wo + l15) * CO + l4 * 8;

  f32x4 acc[8];
#pragma unroll
  for (int nf = 0; nf < 8; nf++) acc[nf] = {0.f, 0.f, 0.f, 0.f};

  bf16x8 aC[4], aN[4];
#pragma unroll
  for (int kc = 0; kc < 4; kc++)
    aC[kc] = *(const bf16x8*)(wbase + kc * 32);

  int dy = 0, dx = 0;
#pragma unroll 1
  for (int p = 0; p < 25; ++p) {
    if (p < 24) {
      const ushort* wnext = wbase + (size_t)(p + 1) * CO * CO;
#pragma unroll
      for (int kc = 0; kc < 4; kc++)
        aN[kc] = *(const bf16x8*)(wnext + kc * 32);
    }
#pragma unroll
    for (int nf = 0; nf < 8; nf++) {
      int pix = (nf + dy) * 20 + dx + l15;
      int base = pix << 7;
      int sw = pix & 15;
      f32x4 y = {0.f, 0.f, 0.f, 0.f};
#pragma unroll
      for (int kc = 0; kc < 4; kc++) {
        bf16x8 bb = *(const bf16x8*)(xt + base + (((kc * 4 + l4) ^ sw) << 3));
        y = __builtin_amdgcn_mfma_f32_16x16x32_bf16(aC[kc], bb, y, 0, 0, 0);
      }
      float ks = kt[(nf << 4) + l15][p];
#pragma unroll
      for (int r = 0; r < 4; r++) acc[nf][r] += ks * y[r];
    }
#pragma unroll
    for (int kc = 0; kc < 4; kc++) aC[kc] = aN[kc];
    if (++dx == 5) { dx = 0; dy++; }
  }

#pragma unroll
  for (int nf = 0; nf < 8; nf++) {
    int gpix = (h0 + nf) * W2 + w0 + l15;
#pragma unroll
    for (int r = 0; r < 4; r++) {
      int o = wo + l4 * 4 + r;
      out[((size_t)b * CO + o) * NPIX2 + gpix] = acc[nf][r] + bias[o];
    }
  }
}

extern "C" void kernel_launch(void* const* d_in, const int* in_sizes, int n_in,
                              void* d_out, int out_size, void* d_ws, size_t ws_size,
                              hipStream_t stream)
{
  (void)in_sizes; (void)n_in; (void)out_size; (void)ws_size;
  const float* input    = (const float*)d_in[0];
  const float* feature  = (const float*)d_in[1];
  const float* conv1_w  = (const float*)d_in[2];
  const float* conv1_b  = (const float*)d_in[3];
  const float* in1_w    = (const float*)d_in[4];
  const float* in1_b    = (const float*)d_in[5];
  const float* prelu1_a = (const float*)d_in[6];
  const float* conv2_w  = (const float*)d_in[7];
  const float* conv2_b  = (const float*)d_in[8];
  const float* in2_w    = (const float*)d_in[9];
  const float* in2_b    = (const float*)d_in[10];
  const float* prelu2_a = (const float*)d_in[11];
  const float* res_w    = (const float*)d_in[12];
  const float* res_b    = (const float*)d_in[13];
  const float* feat_w   = (const float*)d_in[14];
  const float* feat_b   = (const float*)d_in[15];
  const float* pac_w    = (const float*)d_in[16];
  const float* pac_b    = (const float*)d_in[17];
  float* out = (float*)d_out;

  // workspace layout (f32 element offsets); aliases have disjoint lifetimes
  float* ws = (float*)d_ws;
  float*  kern = ws;                              // [0, 589824)  late: kernfin->pacmfma
  ushort* t1h  = (ushort*)ws;                     // alias: apply1->conv2 (294912 f)
  ushort* wt2  = (ushort*)(ws + 294912);          // wt2k->conv2 (73728 f)
  ushort* wt1  = (ushort*)(ws + 368640);          // wt1k->conv1 (147456 f)
  float*  t2   = ws + 589824;                     // 589824
  float*  pws  = ws + 1179648;                    // 2359296 (conv partials / pd2)
  float*  g    = ws + 3538944;                    // 2359296 (featconv->kernpart)
  ushort* xinh = (ushort*)g;                      // alias: cvt_in->conv1 (589824 f)
  ushort* yh   = (ushort*)(ws + 5898240);         // 2359296 ushort
  ushort* wbb  = (ushort*)(ws + 7077888);         // 409600 ushort
  float*  scsh = ws + 7282688;                    // 512 f (end 7283200 f = 29.1MB)
  float*  pd2  = pws;

  // weight/input transforms
  wconv_kernel<<<1600, 256, 0, stream>>>(pac_w, wbb);
  cvt_in_t_kernel<<<B * 36 * 8, 256, 0, stream>>>(input, xinh);
  wtconv_kernel<CIN, 8><<<(9 * 128 * CIN) / 256, 256, 0, stream>>>(conv1_w, wt1);
  wtconv_kernel<CO, 7><<<(9 * 128 * CO) / 256, 256, 0, stream>>>(conv2_w, wt2);

  // conv1 (MFMA) -> IN stats -> apply+PReLU -> NHWC bf16 t1h
  conv3_mfma_kernel<CIN><<<B * NS * 36, 256, 0, stream>>>(xinh, wt1, pws);
  in_stats_kernel<<<B * CO, 256, 0, stream>>>(pws, in1_w, in1_b, scsh);
  in_apply_hwc_kernel<<<B * 36 * 4, 256, 0, stream>>>(pws, scsh, prelu1_a, t1h);
  // conv2 (MFMA) -> reduce+IN2+PReLU -> NCHW f32 t2
  conv3_mfma_kernel<CO><<<B * NS * 36, 256, 0, stream>>>(t1h, wt2, pws);
  reduce_in_prelu_kernel<<<B * CO, 256, 0, stream>>>(
      pws, conv2_b, in2_w, in2_b, prelu2_a, t2);
  // residual 1x1 accumulate into t2 (f32 NCHW)
  conv1x1_kernel<CIN, 4, true><<<B * (CO / 4) * (NPIX1 / 256), 256, 0, stream>>>(
      input, res_w, res_b, t2, NPIX1);
  // bicubic 2x upsample -> NHWC bf16 (LDS transpose)
  upsample_t_kernel<<<B * H2 * 4, 256, 0, stream>>>(t2, yh);
  // guidance g = 1x1(feature), f32 NCHW
  conv1x1_kernel<CO, 8, false><<<B * (CO / 8) * (NPIX2 / 256), 256, 0, stream>>>(
      feature, feat_w, feat_b, g, NPIX2);
  // gaussian kernel
  pac_kern_part_kernel<<<B * 36 * 4, 256, 0, stream>>>(g, pd2);
  pac_kern_fin_kernel<<<B * 36, 256, 0, stream>>>(pd2, kern);
  // PAC conv on matrix cores
  pac_mfma_kernel<<<B * 12 * 6 * 2, 256, 0, stream>>>(yh, kern, wbb, pac_b, out);
}